// Round 1
// baseline (457.837 us; speedup 1.0000x reference)
//
#include <hip/hip_runtime.h>
#include <math.h>

// Router: logits = X[32768,2048] @ W[64,2048]^T ; softmax over 64; stable top-8.
//
// R1: previous kernel was latency-bound (MfmaUtil 6%, VALUBusy 21%, HBM 11%,
// Occupancy 22%): 32 K-tiles x __syncthreads per tile, each barrier drains
// vmcnt(0) (killing the global_load_lds prefetch ~500 cycles after issue), and
// 64 KB LDS capped residency at 2 blocks/CU = 8 waves/CU. This version removes
// ALL barriers from the hot loop:
//  - W (512 KB) is pre-split once by a 64-block prep kernel into f16 hi/lo
//    granules in d_ws, packed so each lane's B-fragment pair (bh,bl) is one
//    contiguous 32 B at  n*8192 + h*4096 + kk*128 + q*32  (L2-resident).
//  - X A-fragments load straight from global to registers (per lane 32 B =
//    2x dwordx4; per wave 16 rows x 128 B of fully-used cache lines),
//    triple-buffered in registers. No LDS in the main loop, no barriers.
//  - Wave = 16 rows x half-K (K-split 2): 4096 waves, 1024 blocks, 4 blocks/CU
//    (LDS 17.4 KB, VGPR <= 128) -> 16 waves/CU, grid exactly 4/CU (no tail).
// Numerics identical to the passing kernel: x,w scaled by 2^12/2^13, exact f16
// 2-splits, 3 MFMAs (hh; hl+lh in a second acc), fp32 accumulators, exact 2^-25
// descale; K-order differs only by the half-split (one fp32 partial add at end).

constexpr int HD = 2048, NE = 64, TOPK = 8;
constexpr float XSC = 4096.f;   // 2^12
constexpr float WSC = 8192.f;   // 2^13
constexpr float DESCALE = 1.0f / (XSC * WSC);   // exact 2^-25

typedef _Float16 f16x8 __attribute__((ext_vector_type(8)));
typedef float f32x4 __attribute__((ext_vector_type(4)));

// ---- W prep: f32 [64][2048] -> packed f16 hi/lo granules in workspace.
// Byte layout: addr = n*8192 + kslot*32 + sel*16, kslot = k>>3 (0..255), sel=hi/lo.
__global__ __launch_bounds__(256)
void wprep_k(const float* __restrict__ W, char* __restrict__ WP) {
  const int n = blockIdx.x, t = threadIdx.x;          // t = k-granule 0..255
  const float* src = W + n * HD + t * 8;
  f16x8 hi, lo;
#pragma unroll
  for (int j = 0; j < 8; ++j) {
    float a = src[j] * WSC;
    _Float16 h = (_Float16)a;
    hi[j] = h;
    lo[j] = (_Float16)(a - (float)h);
  }
  char* dst = WP + n * 8192 + t * 32;
  *(f16x8*)dst = hi;
  *(f16x8*)(dst + 16) = lo;
}

// ---- Main: 1024 blocks x 256 thr. Wave wv: row-group rg=wv>>1 (16 rows),
// k-half h=wv&1 (1024 k = 32 steps of K=32). MFMA 16x16x32_f16:
// A[m=lane&15][k=(lane>>4)*8+j], B[n=lane&15][k], C row=(lane>>4)*4+r, col=lane&15.
__global__ __launch_bounds__(256, 4)
void router_k(const float* __restrict__ X, const char* __restrict__ WP,
              float* __restrict__ probs, float* __restrict__ topv,
              float* __restrict__ topi) {
  __shared__ float part[4][16][68];                   // 17408 B: per-wave partial logits

  const int tid = threadIdx.x, wv = tid >> 6, lane = tid & 63;
  const int m = lane & 15, q = lane >> 4;
  const int rowbase = blockIdx.x * 32;
  const int rg = wv >> 1, h = wv & 1;

  // per-lane A-fragment cursor: row = rowbase + rg*16 + m, k0 = h*1024 + q*8
  const float* xp = X + (size_t)(rowbase + rg * 16 + m) * HD + h * 1024 + q * 8;
  // per-lane B-fragment cursor: n = nt*16 + m (nt via +nt*131072 below)
  const char* wp0 = WP + m * 8192 + h * 4096 + q * 32;

  f32x4 acc_hh[4], acc_cr[4];
#pragma unroll
  for (int nt = 0; nt < 4; ++nt) {
    acc_hh[nt] = {0.f, 0.f, 0.f, 0.f};
    acc_cr[nt] = {0.f, 0.f, 0.f, 0.f};
  }

  f32x4 xaA, xbA, xaB, xbB, xaC, xbC;   // X raw triple-buffer (named: stays in regs)
  f16x8 wf[8];                          // W frags, constant-indexed only

#define LOADX(XA, XB, kk) { XA = *(const f32x4*)(xp + (kk) * 32);          \
                            XB = *(const f32x4*)(xp + (kk) * 32 + 4); }
#define LOADW(kk) { _Pragma("unroll")                                      \
    for (int nt = 0; nt < 4; ++nt) {                                       \
      wf[2*nt]   = *(const f16x8*)(wp0 + nt * 131072 + (kk) * 128);        \
      wf[2*nt+1] = *(const f16x8*)(wp0 + nt * 131072 + (kk) * 128 + 16); } }
#define STEP(XA, XB) {                                                     \
    f16x8 ah, al;                                                          \
    _Pragma("unroll") for (int j = 0; j < 4; ++j) {                        \
      float a = XA[j] * XSC; _Float16 ha = (_Float16)a;                    \
      ah[j] = ha; al[j] = (_Float16)(a - (float)ha);                       \
      float b = XB[j] * XSC; _Float16 hb = (_Float16)b;                    \
      ah[j+4] = hb; al[j+4] = (_Float16)(b - (float)hb); }                 \
    _Pragma("unroll") for (int nt = 0; nt < 4; ++nt) {                     \
      acc_hh[nt] = __builtin_amdgcn_mfma_f32_16x16x32_f16(ah, wf[2*nt],   acc_hh[nt], 0, 0, 0); \
      acc_cr[nt] = __builtin_amdgcn_mfma_f32_16x16x32_f16(ah, wf[2*nt+1], acc_cr[nt], 0, 0, 0); \
      acc_cr[nt] = __builtin_amdgcn_mfma_f32_16x16x32_f16(al, wf[2*nt],   acc_cr[nt], 0, 0, 0); } }

  // software pipeline: X prefetch depth 2 (regs), W just-in-time from L2.
  // 32 steps = 10 iterations x 3 + 2 epilogue steps; all load indices <= 31.
  LOADX(xaA, xbA, 0);
  LOADX(xaB, xbB, 1);
  for (int k3 = 0; k3 < 10; ++k3) {
    const int k0 = 3 * k3;
    LOADX(xaC, xbC, k0 + 2);  LOADW(k0);      STEP(xaA, xbA);
    LOADX(xaA, xbA, k0 + 3);  LOADW(k0 + 1);  STEP(xaB, xbB);
    LOADX(xaB, xbB, k0 + 4);  LOADW(k0 + 2);  STEP(xaC, xbC);
  }
  LOADW(30);  STEP(xaA, xbA);
  LOADW(31);  STEP(xaB, xbB);

#undef LOADX
#undef LOADW
#undef STEP

  // combine the two K-halves via LDS, then per-row softmax + stable top-8.
#pragma unroll
  for (int nt = 0; nt < 4; ++nt)
#pragma unroll
    for (int r = 0; r < 4; ++r)
      part[wv][4 * q + r][nt * 16 + m] = (acc_hh[nt][r] + acc_cr[nt][r]) * DESCALE;
  __syncthreads();

  for (int rr = 0; rr < 8; ++rr) {
    const int rb = wv * 8 + rr;                    // block-local row 0..31
    const int pi = (rb >> 4) * 2, ri = rb & 15;
    const float lg = part[pi][ri][lane] + part[pi + 1][ri][lane];

    float mx = lg;
#pragma unroll
    for (int off = 32; off; off >>= 1)
      mx = fmaxf(mx, __shfl_xor(mx, off, 64));

    const float ex = expf(lg - mx);
    float sm = ex;
#pragma unroll
    for (int off = 32; off; off >>= 1)
      sm += __shfl_xor(sm, off, 64);

    const float p = ex * (1.0f / sm);
    probs[(size_t)(rowbase + rb) * NE + lane] = p;

    // stable rank: #(p_j > p) + #(p_j == p with j < lane) -> matches lax.top_k
    int rank = 0;
#pragma unroll
    for (int j = 0; j < NE; ++j) {
      const float pj = __shfl(p, j, 64);
      rank += (pj > p) || (pj == p && j < lane);
    }
    if (rank < TOPK) {
      topv[(size_t)(rowbase + rb) * TOPK + rank] = p;
      topi[(size_t)(rowbase + rb) * TOPK + rank] = (float)lane;
    }
  }
}

extern "C" void kernel_launch(void* const* d_in, const int* in_sizes, int n_in,
                              void* d_out, int out_size, void* d_ws, size_t ws_size,
                              hipStream_t stream) {
  const float* X = (const float*)d_in[0];
  const float* W = (const float*)d_in[1];
  const int n = in_sizes[0] / HD;          // 32768 tokens

  float* probs = (float*)d_out;
  float* topv  = probs + (size_t)n * NE;
  float* topi  = topv + (size_t)n * TOPK;
  char* WP = (char*)d_ws;                  // 512 KB packed f16 hi/lo W

  hipLaunchKernelGGL(wprep_k, dim3(NE), dim3(256), 0, stream, W, WP);
  hipLaunchKernelGGL(router_k, dim3(n / 32), dim3(256), 0, stream,
                     X, WP, probs, topv, topi);
}

// Round 2
// 428.631 us; speedup vs baseline: 1.0681x; 1.0681x over previous
//
#include <hip/hip_runtime.h>
#include <math.h>

// Router: logits = X[32768,2048] @ W[64,2048]^T ; softmax over 64; stable top-8.
//
// R2 theory: R1 was stalled on per-step W-fragment fetches: issued just-in-time
// (full L2/L3 latency exposed every step by the in-order vmcnt wait) and laid
// out so every W instr touched 32 half-used cache lines (TA serialization +
// 2x L1 fill). Fixes, keeping the f16 2-split numerics bit-identical:
//  - WP re-packed in INSTRUCTION ORDER: fragment (h,kk,nt,sel) is 64 lanes x
//    consecutive 16 B = one fully-coalesced 1 KB load (16 full lines).
//  - W fragments register double-buffered: step k+1's 8 loads issue one full
//    step (~300 cy of MFMA+VALU) before consumption.
//  - G=2 row-groups per wave (32 rows, k-split 2): halves W traffic to 512 MB,
//    24 MFMAs + ~190cy VALU per W fetch. Grid 512 blocks (2/CU), VGPR ~200 ->
//    2 waves/SIMD. X register-pipelined 2 steps ahead (no LDS, no barriers in
//    the hot loop).
// Numerics: x,w scaled by 2^12/2^13, exact f16 2-splits, 3 MFMAs (hh; hl+lh in
// a second acc), fp32 accumulators, exact 2^-25 descale. Same as passing R0/R1.

constexpr int HD = 2048, NE = 64, TOPK = 8;
constexpr float XSC = 4096.f;   // 2^12
constexpr float WSC = 8192.f;   // 2^13
constexpr float DESCALE = 1.0f / (XSC * WSC);   // exact 2^-25

typedef _Float16 f16x8 __attribute__((ext_vector_type(8)));
typedef float f32x4 __attribute__((ext_vector_type(4)));

// ---- W prep: f32 [64][2048] -> instruction-order packed f16 hi/lo fragments.
// Fragment (h,kk,nt,sel): 1024 B = lane (q*16+m) * 16 B, holding
// W[nt*16+m][h*1024 + kk*32 + q*8 + j] (j=0..7), hi (sel=0) / lo (sel=1).
// Byte addr = (((h*32+kk)*4 + nt)*2 + sel)*1024 + (q*16+m)*16 + j*2.
__global__ __launch_bounds__(256)
void wprep_k(const float* __restrict__ W, char* __restrict__ WP) {
  const int b = blockIdx.x;                 // b = h*32 + kk  (64 blocks)
  const int h = b >> 5, kk = b & 31;
  const int t = threadIdx.x;                // t = nt*64 + q*16 + m
  const int nt = t >> 6, q = (t >> 4) & 3, m = t & 15;
  const float* src = W + (size_t)(nt * 16 + m) * HD + h * 1024 + kk * 32 + q * 8;
  f16x8 hi, lo;
#pragma unroll
  for (int j = 0; j < 8; ++j) {
    float a = src[j] * WSC;
    _Float16 ha = (_Float16)a;
    hi[j] = ha;
    lo[j] = (_Float16)(a - (float)ha);
  }
  char* dst = WP + ((size_t)b * 8 + nt * 2) * 1024 + (q * 16 + m) * 16;
  *(f16x8*)dst = hi;
  *(f16x8*)(dst + 1024) = lo;
}

// ---- Main: 512 blocks x 256 thr. Wave wv: rg=wv>>1 (rows rg*32..+31, two
// 16-row MFMA groups), h=wv&1 (k-half, 32 steps of K=32). MFMA 16x16x32_f16:
// A[m=lane&15][k=(lane>>4)*8+j], B[n=lane&15][k], C row=(lane>>4)*4+r, col=lane&15.
__global__ __launch_bounds__(256, 2)
void router_k(const float* __restrict__ X, const char* __restrict__ WP,
              float* __restrict__ probs, float* __restrict__ topv,
              float* __restrict__ topi) {
  __shared__ float part[4][32][68];                 // 34816 B partial logits

  const int tid = threadIdx.x, wv = tid >> 6, lane = tid & 63;
  const int m = lane & 15, q = lane >> 4;
  const int rowbase = blockIdx.x * 64;
  const int rg = wv >> 1, h = wv & 1;

  // X cursors for the two 16-row groups (k = h*1024 + kk*32 + q*8 + j)
  const float* xq0 = X + (size_t)(rowbase + rg * 32 + m) * HD + h * 1024 + q * 8;
  const float* xq1 = xq0 + 16 * HD;
  // W cursor: fragment base for this k-half + this lane's 16 B
  const char* wq = WP + (size_t)h * 262144 + lane * 16;

  f32x4 acc_hh0[4], acc_cr0[4], acc_hh1[4], acc_cr1[4];
#pragma unroll
  for (int nt = 0; nt < 4; ++nt) {
    acc_hh0[nt] = {0.f, 0.f, 0.f, 0.f}; acc_cr0[nt] = {0.f, 0.f, 0.f, 0.f};
    acc_hh1[nt] = {0.f, 0.f, 0.f, 0.f}; acc_cr1[nt] = {0.f, 0.f, 0.f, 0.f};
  }

  // X double-slot (2-step prefetch), W double-buffer (1-step prefetch)
  f32x4 x0aA, x0bA, x1aA, x1bA, x0aB, x0bB, x1aB, x1bB;
  f16x8 w0[8], w1[8];

  // byte offsets relative to cursors; cursors advance 2 steps (256 B X, 16 KB W)
#define LOADX(S, OFF) {                                             \
    x0a##S = *(const f32x4*)((const char*)xq0 + (OFF));             \
    x0b##S = *(const f32x4*)((const char*)xq0 + (OFF) + 16);        \
    x1a##S = *(const f32x4*)((const char*)xq1 + (OFF));             \
    x1b##S = *(const f32x4*)((const char*)xq1 + (OFF) + 16); }
#define LOADW(WF, OFF) { _Pragma("unroll")                          \
    for (int nt = 0; nt < 4; ++nt) {                                \
      WF[2*nt]   = *(const f16x8*)(wq + (OFF) + nt * 2048);         \
      WF[2*nt+1] = *(const f16x8*)(wq + (OFF) + nt * 2048 + 1024); } }
#define STEP(S, WF) {                                               \
    f16x8 ah0, al0, ah1, al1;                                       \
    _Pragma("unroll") for (int j = 0; j < 4; ++j) {                 \
      float a0 = x0a##S[j] * XSC; _Float16 h0 = (_Float16)a0;       \
      ah0[j] = h0; al0[j] = (_Float16)(a0 - (float)h0);             \
      float b0 = x0b##S[j] * XSC; _Float16 g0 = (_Float16)b0;       \
      ah0[j+4] = g0; al0[j+4] = (_Float16)(b0 - (float)g0);         \
      float a1 = x1a##S[j] * XSC; _Float16 h1 = (_Float16)a1;       \
      ah1[j] = h1; al1[j] = (_Float16)(a1 - (float)h1);             \
      float b1 = x1b##S[j] * XSC; _Float16 g1 = (_Float16)b1;       \
      ah1[j+4] = g1; al1[j+4] = (_Float16)(b1 - (float)g1); }       \
    _Pragma("unroll") for (int nt = 0; nt < 4; ++nt) {              \
      acc_hh0[nt] = __builtin_amdgcn_mfma_f32_16x16x32_f16(ah0, WF[2*nt],   acc_hh0[nt], 0, 0, 0); \
      acc_cr0[nt] = __builtin_amdgcn_mfma_f32_16x16x32_f16(ah0, WF[2*nt+1], acc_cr0[nt], 0, 0, 0); \
      acc_cr0[nt] = __builtin_amdgcn_mfma_f32_16x16x32_f16(al0, WF[2*nt],   acc_cr0[nt], 0, 0, 0); \
      acc_hh1[nt] = __builtin_amdgcn_mfma_f32_16x16x32_f16(ah1, WF[2*nt],   acc_hh1[nt], 0, 0, 0); \
      acc_cr1[nt] = __builtin_amdgcn_mfma_f32_16x16x32_f16(ah1, WF[2*nt+1], acc_cr1[nt], 0, 0, 0); \
      acc_cr1[nt] = __builtin_amdgcn_mfma_f32_16x16x32_f16(al1, WF[2*nt],   acc_cr1[nt], 0, 0, 0); } }

  // prologue: X slots A(k=0), B(k=1); W buffer w0(k=0)
  LOADX(A, 0);
  LOADX(B, 128);
  LOADW(w0, 0);

  // steady state: 15 iters x 2 steps (k = 0..29), then tail k = 30,31.
  // Invariant entering iter: xq/wq point at step k0; A=X(k0), B=X(k0+1), w0=W(k0).
  for (int i = 0; i < 15; ++i) {
    LOADW(w1, 8192);        // W(k0+1), 1 step ahead
    STEP(A, w0);            // k0
    LOADX(A, 256);          // X(k0+2), 2 steps ahead
    LOADW(w0, 16384);       // W(k0+2)
    STEP(B, w1);            // k0+1
    LOADX(B, 384);          // X(k0+3)
    xq0 += 64; xq1 += 64; wq += 16384;
  }
  LOADW(w1, 8192);          // W(31)
  STEP(A, w0);              // k=30
  STEP(B, w1);              // k=31

#undef LOADX
#undef LOADW
#undef STEP

  // combine the two K-halves via LDS, then per-row softmax + stable top-8.
#pragma unroll
  for (int nt = 0; nt < 4; ++nt)
#pragma unroll
    for (int r = 0; r < 4; ++r) {
      part[wv][4 * q + r][nt * 16 + m] =
          (acc_hh0[nt][r] + acc_cr0[nt][r]) * DESCALE;
      part[wv][16 + 4 * q + r][nt * 16 + m] =
          (acc_hh1[nt][r] + acc_cr1[nt][r]) * DESCALE;
    }
  __syncthreads();

  for (int rr = 0; rr < 16; ++rr) {
    const int rb = wv * 16 + rr;                  // block-local row 0..63
    const int rgx = rb >> 5, r = rb & 31;
    const float lg = part[2 * rgx][r][lane] + part[2 * rgx + 1][r][lane];

    float mx = lg;
#pragma unroll
    for (int off = 32; off; off >>= 1)
      mx = fmaxf(mx, __shfl_xor(mx, off, 64));

    const float ex = expf(lg - mx);
    float sm = ex;
#pragma unroll
    for (int off = 32; off; off >>= 1)
      sm += __shfl_xor(sm, off, 64);

    const float p = ex * (1.0f / sm);
    probs[(size_t)(rowbase + rb) * NE + lane] = p;

    // stable rank: #(p_j > p) + #(p_j == p with j < lane) -> matches lax.top_k
    int rank = 0;
#pragma unroll
    for (int j = 0; j < NE; ++j) {
      const float pj = __shfl(p, j, 64);
      rank += (pj > p) || (pj == p && j < lane);
    }
    if (rank < TOPK) {
      topv[(size_t)(rowbase + rb) * TOPK + rank] = p;
      topi[(size_t)(rowbase + rb) * TOPK + rank] = (float)lane;
    }
  }
}

extern "C" void kernel_launch(void* const* d_in, const int* in_sizes, int n_in,
                              void* d_out, int out_size, void* d_ws, size_t ws_size,
                              hipStream_t stream) {
  const float* X = (const float*)d_in[0];
  const float* W = (const float*)d_in[1];
  const int n = in_sizes[0] / HD;          // 32768 tokens

  float* probs = (float*)d_out;
  float* topv  = probs + (size_t)n * NE;
  float* topi  = topv + (size_t)n * TOPK;
  char* WP = (char*)d_ws;                  // 512 KB packed f16 hi/lo W fragments

  hipLaunchKernelGGL(wprep_k, dim3(64), dim3(256), 0, stream, W, WP);
  hipLaunchKernelGGL(router_k, dim3(n / 64), dim3(256), 0, stream,
                     X, WP, probs, topv, topi);
}

// Round 3
// 425.825 us; speedup vs baseline: 1.0752x; 1.0066x over previous
//
#include <hip/hip_runtime.h>
#include <math.h>

// Router: logits = X[32768,2048] @ W[64,2048]^T ; softmax over 64; stable top-8.
//
// R3: counted-vmcnt pipeline (guide T3+T4). Evidence: R0/R1/R2 all ~170-200us
// with MfmaUtil<6%, VALU<21%, HBM<11%, occupancy 8-12 waves/CU -> waves are
// ~90% stalled in s_waitcnt (per-wave serialized memory latency). R1/R2's reg
// pipelines were collapsed by regalloc (VGPR_Count 64/84 << pipeline needs);
// R0's __syncthreads drained vmcnt(0) each tile, killing its gll prefetch.
// Fix: R0's structure, but
//  - W pre-split once into fragment-ordered f16 hi/lo (wprep_k, from R2) and
//    staged with global_load_lds (no VALU convert / ds_writes in the loop),
//    double-buffered (L2-resident, 1-tile lead).
//  - X triple-buffered via global_load_lds, issued 2 tiles ahead (~1000+ cy
//    cover vs ~900 cy HBM latency).
//  - Raw s_barrier + inline-asm s_waitcnt vmcnt(4) per tile (vmcnt(0) only at
//    the last tile): the X(t+1)/W(t+1) loads stay in flight ACROSS barriers.
//    Issue order pinned (W older than X) with sched_barrier(0) so the count 4
//    == "X(t+1) outstanding" is exact. LDS 80KB -> 2 blocks/CU.
// Numerics: identical accumulation order to the 422us baseline (hh + cross
// accs, 3 MFMAs per nt per K=32 step, exact 2^-25 descale).

constexpr int HD = 2048, NE = 64, RPB = 64, BK = 64, NT = HD / BK, TOPK = 8;
constexpr float XSC = 4096.f;     // 2^12
constexpr float WSC = 8192.f;     // 2^13
constexpr float DESCALE = 1.0f / (XSC * WSC);   // exact 2^-25

typedef _Float16 f16x8 __attribute__((ext_vector_type(8)));
typedef float f32x4 __attribute__((ext_vector_type(4)));
typedef void __attribute__((address_space(1)))* gas_t;
typedef void __attribute__((address_space(3)))* las_t;

__device__ __forceinline__ void gload_lds16(const void* g, void* l) {
  __builtin_amdgcn_global_load_lds((gas_t)(uintptr_t)g, (las_t)l, 16, 0, 0);
}

// ---- W prep (R2 verbatim, benched PASS): f32 [64][2048] -> fragment-ordered
// f16 hi/lo. Fragment for global K-step g (=k/32), expert-tile nt, sel(hi/lo):
// byte addr = (g*8 + nt*2 + sel)*1024 + lane*16, lane = q*16+m holding
// W[nt*16+m][g*32 + q*8 + j], j=0..7.
__global__ __launch_bounds__(256)
void wprep_k(const float* __restrict__ W, char* __restrict__ WP) {
  const int b = blockIdx.x;                 // b = global K-step g (64 blocks)
  const int t = threadIdx.x;                // t = nt*64 + q*16 + m
  const int nt = t >> 6, q = (t >> 4) & 3, m = t & 15;
  const float* src = W + (size_t)(nt * 16 + m) * HD + b * 32 + q * 8;
  f16x8 hi, lo;
#pragma unroll
  for (int j = 0; j < 8; ++j) {
    float a = src[j] * WSC;
    _Float16 ha = (_Float16)a;
    hi[j] = ha;
    lo[j] = (_Float16)(a - (float)ha);
  }
  char* dst = WP + ((size_t)b * 8 + nt * 2) * 1024 + (q * 16 + m) * 16;
  *(f16x8*)dst = hi;
  *(f16x8*)(dst + 1024) = lo;
}

// ---- Main: 512 blocks x 256 thr (4 waves). Wave wv owns rows 16wv..16wv+15,
// full K as 32 BK=64 tiles (2 K=32 MFMA steps each).
// MFMA 16x16x32_f16: A[m=lane&15][k=(lane>>4)*8+j], B[n=lane&15][k],
// C row=(lane>>4)*4+r, col=lane&15 (m91-verified, same as baseline).
__global__ __launch_bounds__(256, 2)
void router_k(const float* __restrict__ X, const char* __restrict__ WP,
              float* __restrict__ probs, float* __restrict__ topv,
              float* __restrict__ topi) {
  __shared__ float4 smem4[5120];            // 81920 B
  char* smem = (char*)smem4;
  // xbuf[3] @ 0 (3*16384) ; wbuf[2] @ 49152 (2*16384: 16 frags x 1024 each)

  const int tid = threadIdx.x, wv = tid >> 6, lane = tid & 63;
  const int m_l = lane & 15, q_l = lane >> 4;
  const int rowbase = blockIdx.x * RPB;

  // X staging (R0-verbatim swizzle, benched 0 bank conflicts): wave wv executes
  // gll instrs i = 4m+wv; lane covers row 16m+4wv+q_l, 16B-granule
  // kq = m_l ^ ((4wv+q_l)&15). Dest is wave-uniform (4m+wv)*1024, src per-lane.
  const int kq_st = m_l ^ ((4 * wv + q_l) & 15);
  const float* gx = X + (size_t)(rowbase + 4 * wv + q_l) * HD + kq_st * 4;
  // W staging: tile t = 16 frags of 1 KB at WP + t*16384 + f*1024; wave wv
  // stages f = 4wv..4wv+3 (identity copy, src per-lane = +lane*16).
  const char* gw = WP + lane * 16;

  f32x4 acc_hh[4], acc_cr[4];
#pragma unroll
  for (int nt = 0; nt < 4; ++nt) {
    acc_hh[nt] = {0.f, 0.f, 0.f, 0.f};
    acc_cr[nt] = {0.f, 0.f, 0.f, 0.f};
  }

  // ---- prologue: issue W(0) [4 gll], then X(0) [4], then X(1) [4].
#pragma unroll
  for (int j = 0; j < 4; ++j)
    gload_lds16(gw + (4 * wv + j) * 1024, smem + 49152 + (4 * wv + j) * 1024);
  __builtin_amdgcn_sched_barrier(0);
#pragma unroll
  for (int m = 0; m < 4; ++m)
    gload_lds16(gx + (size_t)m * 16 * HD, smem + (4 * m + wv) * 1024);
  __builtin_amdgcn_sched_barrier(0);
#pragma unroll
  for (int m = 0; m < 4; ++m)
    gload_lds16(gx + (size_t)m * 16 * HD + BK, smem + 16384 + (4 * m + wv) * 1024);
  __builtin_amdgcn_sched_barrier(0);

  int xc = 0, xn = 2;                       // compute buf = t%3, stage buf = (t+2)%3
  for (int t = 0; t < NT; ++t) {
    // need X(t), W(t) landed. Outstanding (old->young): [X(t), W(t), X(t+1)]
    // (steady state) -> instrs younger than W(t) = 4. Never 0 until the tail.
    if (t == NT - 1) {
      asm volatile("s_waitcnt vmcnt(0)" ::: "memory");
    } else {
      asm volatile("s_waitcnt vmcnt(4)" ::: "memory");
    }
    __builtin_amdgcn_s_barrier();           // all waves: bufs(t) ready, bufs(t-1) free
    __builtin_amdgcn_sched_barrier(0);

    if (t + 1 < NT) {                       // stage W(t+1) -> wbuf[(t+1)&1]
      char* wd = smem + 49152 + ((t + 1) & 1) * 16384;
      const char* ws = gw + (size_t)(t + 1) * 16384;
#pragma unroll
      for (int j = 0; j < 4; ++j)
        gload_lds16(ws + (4 * wv + j) * 1024, wd + (4 * wv + j) * 1024);
    }
    __builtin_amdgcn_sched_barrier(0);      // keep W glls older than X glls
    if (t + 2 < NT) {                       // stage X(t+2) -> xbuf[xn]
      char* xd = smem + xn * 16384;
#pragma unroll
      for (int m = 0; m < 4; ++m)
        gload_lds16(gx + (size_t)m * 16 * HD + (t + 2) * BK, xd + (4 * m + wv) * 1024);
    }
    __builtin_amdgcn_sched_barrier(0);

    // ---- compute tile t from xbuf[xc], wbuf[t&1]
    char* xcur = smem + xc * 16384;
    char* wcur = smem + 49152 + (t & 1) * 16384;
#pragma unroll
    for (int s = 0; s < 2; ++s) {
      const int row_l = 16 * wv + m_l;
      const int kq0 = 8 * s + 2 * q_l;
      const int G0 = row_l * 16 + (kq0 ^ m_l);
      const int G1 = row_l * 16 + ((kq0 + 1) ^ m_l);
      f32x4 xa = *(const f32x4*)(xcur + G0 * 16);   // k +0..3
      f32x4 xb = *(const f32x4*)(xcur + G1 * 16);   // k +4..7
      f16x8 ah, al;
#pragma unroll
      for (int j = 0; j < 4; ++j) {
        float a = xa[j] * XSC; _Float16 ha = (_Float16)a;
        ah[j] = ha; al[j] = (_Float16)(a - (float)ha);
        float b = xb[j] * XSC; _Float16 hb = (_Float16)b;
        ah[j + 4] = hb; al[j + 4] = (_Float16)(b - (float)hb);
      }
#pragma unroll
      for (int nt = 0; nt < 4; ++nt) {
        f16x8 bh = *(const f16x8*)(wcur + (s * 8 + nt * 2) * 1024 + lane * 16);
        f16x8 bl = *(const f16x8*)(wcur + (s * 8 + nt * 2 + 1) * 1024 + lane * 16);
        acc_hh[nt] = __builtin_amdgcn_mfma_f32_16x16x32_f16(ah, bh, acc_hh[nt], 0, 0, 0);
        acc_cr[nt] = __builtin_amdgcn_mfma_f32_16x16x32_f16(ah, bl, acc_cr[nt], 0, 0, 0);
        acc_cr[nt] = __builtin_amdgcn_mfma_f32_16x16x32_f16(al, bh, acc_cr[nt], 0, 0, 0);
      }
    }
    xc = (xc + 1 < 3) ? xc + 1 : 0;
    xn = (xn + 1 < 3) ? xn + 1 : 0;
  }

  __syncthreads();                      // everyone done with bufs
  float* plds = (float*)smem;           // logits [64][68] fp32 (17.4 KB)
#pragma unroll
  for (int nt = 0; nt < 4; ++nt)
#pragma unroll
    for (int r = 0; r < 4; ++r)
      plds[(16 * wv + 4 * q_l + r) * 68 + nt * 16 + m_l] =
          (acc_hh[nt][r] + acc_cr[nt][r]) * DESCALE;
  __syncthreads();

  // per-row softmax + stable top-8; wave wv owns rows 16wv..16wv+15, lane==expert
  for (int rr = 0; rr < 16; ++rr) {
    const int row_l = wv * 16 + rr;
    const float lg = plds[row_l * 68 + lane];

    float mx = lg;
#pragma unroll
    for (int off = 32; off; off >>= 1)
      mx = fmaxf(mx, __shfl_xor(mx, off, 64));

    const float ex = expf(lg - mx);
    float sm = ex;
#pragma unroll
    for (int off = 32; off; off >>= 1)
      sm += __shfl_xor(sm, off, 64);

    const float p = ex * (1.0f / sm);
    probs[(size_t)(rowbase + row_l) * NE + lane] = p;

    // stable rank: #(p_j > p) + #(p_j == p with j < lane) -> matches lax.top_k
    int rank = 0;
#pragma unroll
    for (int j = 0; j < NE; ++j) {
      const float pj = __shfl(p, j, 64);
      rank += (pj > p) || (pj == p && j < lane);
    }
    if (rank < TOPK) {
      topv[(size_t)(rowbase + row_l) * TOPK + rank] = p;
      topi[(size_t)(rowbase + row_l) * TOPK + rank] = (float)lane;
    }
  }
}

extern "C" void kernel_launch(void* const* d_in, const int* in_sizes, int n_in,
                              void* d_out, int out_size, void* d_ws, size_t ws_size,
                              hipStream_t stream) {
  const float* X = (const float*)d_in[0];
  const float* W = (const float*)d_in[1];
  const int n = in_sizes[0] / HD;          // 32768 tokens

  float* probs = (float*)d_out;
  float* topv  = probs + (size_t)n * NE;
  float* topi  = topv + (size_t)n * TOPK;
  char* WP = (char*)d_ws;                  // 512 KB packed f16 hi/lo W fragments

  hipLaunchKernelGGL(wprep_k, dim3(64), dim3(256), 0, stream, W, WP);
  hipLaunchKernelGGL(router_k, dim3(n / RPB), dim3(256), 0, stream,
                     X, WP, probs, topv, topi);
}

// Round 4
// 409.236 us; speedup vs baseline: 1.1188x; 1.0405x over previous
//
#include <hip/hip_runtime.h>
#include <math.h>

// Router: logits = X[32768,2048] @ W[64,2048]^T ; softmax over 64; stable top-8.
//
// R4 theory: R3 (counted vmcnt, 3-deep gll pipeline) timed IDENTICAL to R0
// (169.7 vs 169.6us) -> wait placement was never the limiter. All structures
// deliver ~5 B/cy/CU (X 268MB + W-stream 256MB = 524MB / 170us = 3.1 TB/s);
// m13 copy-peak is only 10.25 B/cy/CU. So: cut bytes + use the copy-class
// delivery pattern (plain deep-pipelined coalesced reg loads).
//  - W lives in REGISTERS: 8-way K-split, wave owns k-slice of 128 as f16
//    hi/lo fragments (128 VGPR), loaded once per k-phase (2 phases = K 2048).
//    W aggregate traffic halves: 256 blocks x 512 KB = 128 MB (L2-resident).
//  - X: plain dwordx4 reg loads, 16 rows x 128 B fully-used lines per step,
//    8 loads in flight, next chunk prefetched during current chunk's MFMAs.
//    No global_load_lds, no barriers in the K-loop.
//  - Block = 512 thr / 8 waves = 128 rows in 8 chunks of 16; per chunk a
//    small LDS staging + 2 __syncthreads reduces the 8 k-slices.
// Numerics: same exact-f16-2-split scheme as all passing rounds (x*2^12,
// w*2^13, hh + cross accs, fp32 partials, exact 2^-25 descale).

constexpr int HD = 2048, NE = 64, TOPK = 8;
constexpr float XSC = 4096.f;   // 2^12
constexpr float WSC = 8192.f;   // 2^13
constexpr float DESCALE = 1.0f / (XSC * WSC);   // exact 2^-25

typedef _Float16 f16x8 __attribute__((ext_vector_type(8)));
typedef float f32x4 __attribute__((ext_vector_type(4)));

// ---- W prep (R2/R3 verbatim, benched PASS twice): f32 [64][2048] ->
// fragment-ordered f16 hi/lo. For global K-group g (=k/32), expert-tile nt,
// sel(hi/lo): byte addr = (g*8 + nt*2 + sel)*1024 + lane*16, lane = q*16+m
// holding W[nt*16+m][g*32 + q*8 + j], j=0..7.
__global__ __launch_bounds__(256)
void wprep_k(const float* __restrict__ W, char* __restrict__ WP) {
  const int b = blockIdx.x;                 // b = global K-group g (64 blocks)
  const int t = threadIdx.x;                // t = nt*64 + q*16 + m
  const int nt = t >> 6, q = (t >> 4) & 3, m = t & 15;
  const float* src = W + (size_t)(nt * 16 + m) * HD + b * 32 + q * 8;
  f16x8 hi, lo;
#pragma unroll
  for (int j = 0; j < 8; ++j) {
    float a = src[j] * WSC;
    _Float16 ha = (_Float16)a;
    hi[j] = ha;
    lo[j] = (_Float16)(a - (float)ha);
  }
  char* dst = WP + ((size_t)b * 8 + nt * 2) * 1024 + (q * 16 + m) * 16;
  *(f16x8*)dst = hi;
  *(f16x8*)(dst + 1024) = lo;
}

// ---- Main: 256 blocks x 512 thr (8 waves). Wave wv owns k-slice
// [p*1024 + wv*128, +128) in phase p; block owns rows blockIdx.x*128..+127,
// processed in 8 chunks of 16 rows. MFMA 16x16x32_f16 (m91-verified layout):
// A[m=lane&15][k=(lane>>4)*8+j], B[n=lane&15][k], C row=(lane>>4)*4+r,
// col=lane&15.
__global__ __launch_bounds__(512, 2)
void router_k(const float* __restrict__ X, const char* __restrict__ WP,
              float* __restrict__ probs, float* __restrict__ topv,
              float* __restrict__ topi) {
  __shared__ float stage[8][16][68];      // 34816 B: per-wave chunk partials
  __shared__ float logacc[128][68];       // 34816 B: block logits accumulator

  const int tid = threadIdx.x, wv = tid >> 6, lane = tid & 63;
  const int m = lane & 15, q = lane >> 4;
  const int rowbase = blockIdx.x * 128;

  for (int p = 0; p < 2; ++p) {
    // ---- W k-slice into registers: K-groups g = p*32 + wv*4 + s.
    // 32 frag-pairs x 16 B/lane = 128 VGPR, fully static indexing.
    f16x8 bh[4][4], bl[4][4];
#pragma unroll
    for (int s = 0; s < 4; ++s)
#pragma unroll
      for (int nt = 0; nt < 4; ++nt) {
        const char* wp =
            WP + ((size_t)(p * 32 + wv * 4 + s) * 8 + nt * 2) * 1024 + lane * 16;
        bh[s][nt] = *(const f16x8*)wp;
        bl[s][nt] = *(const f16x8*)(wp + 1024);
      }

    // X cursor: row = rowbase + chunk*16 + m, k = p*1024 + wv*128 + q*8 (+s*32)
    const float* xp = X + (size_t)(rowbase + m) * HD + p * 1024 + wv * 128 + q * 8;

    // preload chunk 0 (8 independent dwordx4 in flight)
    f32x4 xa[4], xb[4];
#pragma unroll
    for (int s = 0; s < 4; ++s) {
      xa[s] = *(const f32x4*)(xp + s * 32);
      xb[s] = *(const f32x4*)(xp + s * 32 + 4);
    }

    for (int c = 0; c < 8; ++c) {
      f32x4 acc_hh[4], acc_cr[4];
#pragma unroll
      for (int nt = 0; nt < 4; ++nt) {
        acc_hh[nt] = {0.f, 0.f, 0.f, 0.f};
        acc_cr[nt] = {0.f, 0.f, 0.f, 0.f};
      }

#pragma unroll
      for (int s = 0; s < 4; ++s) {
        f32x4 ca = xa[s], cb = xb[s];
        if (c + 1 < 8) {                      // prefetch chunk c+1, slot s
          xa[s] = *(const f32x4*)(xp + 16 * HD + s * 32);
          xb[s] = *(const f32x4*)(xp + 16 * HD + s * 32 + 4);
        }
        f16x8 ah, al;
#pragma unroll
        for (int j = 0; j < 4; ++j) {
          float a = ca[j] * XSC; _Float16 ha = (_Float16)a;
          ah[j] = ha; al[j] = (_Float16)(a - (float)ha);
          float b = cb[j] * XSC; _Float16 hb = (_Float16)b;
          ah[j + 4] = hb; al[j + 4] = (_Float16)(b - (float)hb);
        }
#pragma unroll
        for (int nt = 0; nt < 4; ++nt) {
          acc_hh[nt] = __builtin_amdgcn_mfma_f32_16x16x32_f16(ah, bh[s][nt], acc_hh[nt], 0, 0, 0);
          acc_cr[nt] = __builtin_amdgcn_mfma_f32_16x16x32_f16(ah, bl[s][nt], acc_cr[nt], 0, 0, 0);
          acc_cr[nt] = __builtin_amdgcn_mfma_f32_16x16x32_f16(al, bh[s][nt], acc_cr[nt], 0, 0, 0);
        }
      }
      xp += 16 * HD;

      // stage this wave's k-slice partial for the chunk
#pragma unroll
      for (int nt = 0; nt < 4; ++nt)
#pragma unroll
        for (int r = 0; r < 4; ++r)
          stage[wv][q * 4 + r][nt * 16 + m] =
              (acc_hh[nt][r] + acc_cr[nt][r]) * DESCALE;
      __syncthreads();

      // reduce 8 slices: wave wv owns chunk-rows wv*2, wv*2+1 (lane = expert)
#pragma unroll
      for (int rr = 0; rr < 2; ++rr) {
        const int r = wv * 2 + rr;
        float v = stage[0][r][lane];
#pragma unroll
        for (int s = 1; s < 8; ++s) v += stage[s][r][lane];
        if (p == 0) logacc[c * 16 + r][lane] = v;
        else        logacc[c * 16 + r][lane] += v;
      }
      __syncthreads();                      // stage reusable next chunk
    }
  }

  // ---- per-row softmax + stable top-8; wave wv owns rows wv*16..wv*16+15
  for (int rr = 0; rr < 16; ++rr) {
    const int row_l = wv * 16 + rr;
    const float lg = logacc[row_l][lane];

    float mx = lg;
#pragma unroll
    for (int off = 32; off; off >>= 1)
      mx = fmaxf(mx, __shfl_xor(mx, off, 64));

    const float ex = expf(lg - mx);
    float sm = ex;
#pragma unroll
    for (int off = 32; off; off >>= 1)
      sm += __shfl_xor(sm, off, 64);

    const float p = ex * (1.0f / sm);
    probs[(size_t)(rowbase + row_l) * NE + lane] = p;

    // stable rank: #(p_j > p) + #(p_j == p with j < lane) -> matches lax.top_k
    int rank = 0;
#pragma unroll
    for (int j = 0; j < NE; ++j) {
      const float pj = __shfl(p, j, 64);
      rank += (pj > p) || (pj == p && j < lane);
    }
    if (rank < TOPK) {
      topv[(size_t)(rowbase + row_l) * TOPK + rank] = p;
      topi[(size_t)(rowbase + row_l) * TOPK + rank] = (float)lane;
    }
  }
}

extern "C" void kernel_launch(void* const* d_in, const int* in_sizes, int n_in,
                              void* d_out, int out_size, void* d_ws, size_t ws_size,
                              hipStream_t stream) {
  const float* X = (const float*)d_in[0];
  const float* W = (const float*)d_in[1];
  const int n = in_sizes[0] / HD;          // 32768 tokens

  float* probs = (float*)d_out;
  float* topv  = probs + (size_t)n * NE;
  float* topi  = topv + (size_t)n * TOPK;
  char* WP = (char*)d_ws;                  // 512 KB packed f16 hi/lo W fragments

  hipLaunchKernelGGL(wprep_k, dim3(64), dim3(256), 0, stream, W, WP);
  hipLaunchKernelGGL(router_k, dim3(n / 128), dim3(512), 0, stream,
                     X, WP, probs, topv, topi);
}

// Round 5
// 406.990 us; speedup vs baseline: 1.1249x; 1.0055x over previous
//
#include <hip/hip_runtime.h>
#include <math.h>

// Router: logits = X[32768,2048] @ W[64,2048]^T ; softmax over 64; stable top-8.
//
// R5 theory: delivery ledger across rounds: R1 (barrier-free streaming) hit
// 6.3 TB/s delivered (= m13 ceiling, perfectly BW-bound on 1.27 GB); R0/R3
// (gll+barriers) 3.1 TB/s; R4 (reg loads, 2x __syncthreads per chunk) 2.6 TB/s
// on the minimal 396 MB. hipcc emits s_waitcnt vmcnt(0) at __syncthreads ->
// R4's chunk-c+1 prefetch is force-drained twice per chunk; all 8 waves stall
// in lockstep on cold loads every 16 rows. Fix (ONLY change vs R4): raw
// s_barrier preceded by inline-asm lgkmcnt(0) only — register-destined global
// loads stay outstanding ACROSS the chunk barriers (their vmcnt waits remain
// compiler-counted at first use). sched_barrier(0) fences stop the scheduler
// from sinking prefetch past the barrier region. Bytes: X 268 MB + W 128 MB
// = 396 MB -> 63 us at ceiling.
// Numerics: identical to R4 (PASS, absmax 2.4e-4): x*2^12 / w*2^13 exact f16
// 2-splits, 3 MFMAs (hh; hl+lh in second acc), fp32 partials, exact 2^-25
// descale, same reduction order.

constexpr int HD = 2048, NE = 64, TOPK = 8;
constexpr float XSC = 4096.f;   // 2^12
constexpr float WSC = 8192.f;   // 2^13
constexpr float DESCALE = 1.0f / (XSC * WSC);   // exact 2^-25

typedef _Float16 f16x8 __attribute__((ext_vector_type(8)));
typedef float f32x4 __attribute__((ext_vector_type(4)));

// ---- W prep (benched PASS 3x): f32 [64][2048] -> fragment-ordered f16 hi/lo.
// For global K-group g (=k/32), expert-tile nt, sel(hi/lo):
// byte addr = (g*8 + nt*2 + sel)*1024 + lane*16, lane = q*16+m holding
// W[nt*16+m][g*32 + q*8 + j], j=0..7.
__global__ __launch_bounds__(256)
void wprep_k(const float* __restrict__ W, char* __restrict__ WP) {
  const int b = blockIdx.x;                 // b = global K-group g (64 blocks)
  const int t = threadIdx.x;                // t = nt*64 + q*16 + m
  const int nt = t >> 6, q = (t >> 4) & 3, m = t & 15;
  const float* src = W + (size_t)(nt * 16 + m) * HD + b * 32 + q * 8;
  f16x8 hi, lo;
#pragma unroll
  for (int j = 0; j < 8; ++j) {
    float a = src[j] * WSC;
    _Float16 ha = (_Float16)a;
    hi[j] = ha;
    lo[j] = (_Float16)(a - (float)ha);
  }
  char* dst = WP + ((size_t)b * 8 + nt * 2) * 1024 + (q * 16 + m) * 16;
  *(f16x8*)dst = hi;
  *(f16x8*)(dst + 1024) = lo;
}

// ---- Main: 256 blocks x 512 thr (8 waves, 1 block/CU). Wave wv owns k-slice
// [p*1024 + wv*128, +128) in phase p; block owns rows blockIdx.x*128..+127 in
// 8 chunks of 16 rows. MFMA 16x16x32_f16 (m91-verified layout):
// A[m=lane&15][k=(lane>>4)*8+j], B[n=lane&15][k], C row=(lane>>4)*4+r,
// col=lane&15.
__global__ __launch_bounds__(512, 2)
void router_k(const float* __restrict__ X, const char* __restrict__ WP,
              float* __restrict__ probs, float* __restrict__ topv,
              float* __restrict__ topi) {
  __shared__ float stage[8][16][68];      // 34816 B: per-wave chunk partials
  __shared__ float logacc[128][68];       // 34816 B: block logits accumulator

  const int tid = threadIdx.x, wv = tid >> 6, lane = tid & 63;
  const int m = lane & 15, q = lane >> 4;
  const int rowbase = blockIdx.x * 128;

  for (int p = 0; p < 2; ++p) {
    // ---- W k-slice into registers: K-groups g = p*32 + wv*4 + s.
    // 32 frag-pairs x 16 B/lane = 128 VGPR, fully static indexing.
    f16x8 bh[4][4], bl[4][4];
#pragma unroll
    for (int s = 0; s < 4; ++s)
#pragma unroll
      for (int nt = 0; nt < 4; ++nt) {
        const char* wp =
            WP + ((size_t)(p * 32 + wv * 4 + s) * 8 + nt * 2) * 1024 + lane * 16;
        bh[s][nt] = *(const f16x8*)wp;
        bl[s][nt] = *(const f16x8*)(wp + 1024);
      }

    // X cursor: row = rowbase + chunk*16 + m, k = p*1024 + wv*128 + q*8 (+s*32)
    const float* xp = X + (size_t)(rowbase + m) * HD + p * 1024 + wv * 128 + q * 8;

    // preload chunk 0 (8 independent dwordx4 in flight)
    f32x4 xa[4], xb[4];
#pragma unroll
    for (int s = 0; s < 4; ++s) {
      xa[s] = *(const f32x4*)(xp + s * 32);
      xb[s] = *(const f32x4*)(xp + s * 32 + 4);
    }

    for (int c = 0; c < 8; ++c) {
      f32x4 acc_hh[4], acc_cr[4];
#pragma unroll
      for (int nt = 0; nt < 4; ++nt) {
        acc_hh[nt] = {0.f, 0.f, 0.f, 0.f};
        acc_cr[nt] = {0.f, 0.f, 0.f, 0.f};
      }

#pragma unroll
      for (int s = 0; s < 4; ++s) {
        f32x4 ca = xa[s], cb = xb[s];
        if (c + 1 < 8) {                      // prefetch chunk c+1, slot s
          xa[s] = *(const f32x4*)(xp + 16 * HD + s * 32);
          xb[s] = *(const f32x4*)(xp + 16 * HD + s * 32 + 4);
        }
        f16x8 ah, al;
#pragma unroll
        for (int j = 0; j < 4; ++j) {
          float a = ca[j] * XSC; _Float16 ha = (_Float16)a;
          ah[j] = ha; al[j] = (_Float16)(a - (float)ha);
          float b = cb[j] * XSC; _Float16 hb = (_Float16)b;
          ah[j + 4] = hb; al[j + 4] = (_Float16)(b - (float)hb);
        }
#pragma unroll
        for (int nt = 0; nt < 4; ++nt) {
          acc_hh[nt] = __builtin_amdgcn_mfma_f32_16x16x32_f16(ah, bh[s][nt], acc_hh[nt], 0, 0, 0);
          acc_cr[nt] = __builtin_amdgcn_mfma_f32_16x16x32_f16(ah, bl[s][nt], acc_cr[nt], 0, 0, 0);
          acc_cr[nt] = __builtin_amdgcn_mfma_f32_16x16x32_f16(al, bh[s][nt], acc_cr[nt], 0, 0, 0);
        }
      }
      xp += 16 * HD;
      __builtin_amdgcn_sched_barrier(0);    // keep c+1 prefetch issued HERE

      // stage this wave's k-slice partial for the chunk
#pragma unroll
      for (int nt = 0; nt < 4; ++nt)
#pragma unroll
        for (int r = 0; r < 4; ++r)
          stage[wv][q * 4 + r][nt * 16 + m] =
              (acc_hh[nt][r] + acc_cr[nt][r]) * DESCALE;

      // barrier WITHOUT vmcnt drain: LDS-only wait + raw s_barrier.
      asm volatile("s_waitcnt lgkmcnt(0)" ::: "memory");
      __builtin_amdgcn_s_barrier();
      __builtin_amdgcn_sched_barrier(0);

      // reduce 8 slices: wave wv owns chunk-rows wv*2, wv*2+1 (lane = expert)
#pragma unroll
      for (int rr = 0; rr < 2; ++rr) {
        const int r = wv * 2 + rr;
        float v = stage[0][r][lane];
#pragma unroll
        for (int s = 1; s < 8; ++s) v += stage[s][r][lane];
        if (p == 0) logacc[c * 16 + r][lane] = v;
        else        logacc[c * 16 + r][lane] += v;
      }

      // second barrier (stage WAR for chunk c+1), again lgkm-only.
      asm volatile("s_waitcnt lgkmcnt(0)" ::: "memory");
      __builtin_amdgcn_s_barrier();
      __builtin_amdgcn_sched_barrier(0);
    }
  }

  __syncthreads();                          // once, before epilogue (harmless)

  // ---- per-row softmax + stable top-8; wave wv owns rows wv*16..wv*16+15
  for (int rr = 0; rr < 16; ++rr) {
    const int row_l = wv * 16 + rr;
    const float lg = logacc[row_l][lane];

    float mx = lg;
#pragma unroll
    for (int off = 32; off; off >>= 1)
      mx = fmaxf(mx, __shfl_xor(mx, off, 64));

    const float ex = expf(lg - mx);
    float sm = ex;
#pragma unroll
    for (int off = 32; off; off >>= 1)
      sm += __shfl_xor(sm, off, 64);

    const float p = ex * (1.0f / sm);
    probs[(size_t)(rowbase + row_l) * NE + lane] = p;

    // stable rank: #(p_j > p) + #(p_j == p with j < lane) -> matches lax.top_k
    int rank = 0;
#pragma unroll
    for (int j = 0; j < NE; ++j) {
      const float pj = __shfl(p, j, 64);
      rank += (pj > p) || (pj == p && j < lane);
    }
    if (rank < TOPK) {
      topv[(size_t)(rowbase + row_l) * TOPK + rank] = p;
      topi[(size_t)(rowbase + row_l) * TOPK + rank] = (float)lane;
    }
  }
}

extern "C" void kernel_launch(void* const* d_in, const int* in_sizes, int n_in,
                              void* d_out, int out_size, void* d_ws, size_t ws_size,
                              hipStream_t stream) {
  const float* X = (const float*)d_in[0];
  const float* W = (const float*)d_in[1];
  const int n = in_sizes[0] / HD;          // 32768 tokens

  float* probs = (float*)d_out;
  float* topv  = probs + (size_t)n * NE;
  float* topi  = topv + (size_t)n * TOPK;
  char* WP = (char*)d_ws;                  // 512 KB packed f16 hi/lo W fragments

  hipLaunchKernelGGL(wprep_k, dim3(64), dim3(256), 0, stream, W, WP);
  hipLaunchKernelGGL(router_k, dim3(n / 128), dim3(512), 0, stream,
                     X, WP, probs, topv, topi);
}